// Round 4
// baseline (448.318 us; speedup 1.0000x reference)
//
#include <hip/hip_runtime.h>
#include <math.h>
#include <stdint.h>

typedef __attribute__((ext_vector_type(8))) short bf16x8;
typedef __attribute__((ext_vector_type(4))) float floatx4;

static __device__ __forceinline__ unsigned short f32_to_bf16_rne(float f) {
    union { float f; uint32_t u; } v; v.f = f;
    uint32_t u = v.u;
    return (unsigned short)((u + 0x7fffu + ((u >> 16) & 1u)) >> 16);
}
static __device__ __forceinline__ float bf16_to_f32(unsigned short h) {
    union { uint32_t u; float f; } v; v.u = ((uint32_t)h) << 16;
    return v.f;
}

// ---------------------------------------------------------------------------
// Prep: W1a (50x318) -> hi/lo bf16, fragment-ordered for direct global reads:
// Bpre[ks][part][kq][n][8 bf16]; idx = (((ks*2+p)*4+kq)*64+n)*8+e; 40960 elems.
// ---------------------------------------------------------------------------
__global__ void prep_w(const float* __restrict__ W1a, unsigned short* __restrict__ Bpre) {
    int idx = blockIdx.x * 256 + threadIdx.x;
    if (idx >= 40960) return;
    int e  = idx & 7;
    int n  = (idx >> 3) & 63;
    int kq = (idx >> 9) & 3;
    int p  = (idx >> 11) & 1;
    int ks = idx >> 12;
    int k  = ks * 32 + kq * 8 + e;
    float w = (n < 50 && k < 318) ? W1a[n * 318 + k] : 0.0f;
    unsigned short hi = f32_to_bf16_rne(w);
    Bpre[idx] = (p == 0) ? hi : f32_to_bf16_rne(w - bf16_to_f32(hi));
}

// ---------------------------------------------------------------------------
// Kernel A: 64 tokens/block, 8192 blocks, 256 threads (4 waves x 16 rows).
// K split into 2 stages of 160 floats -> LDS tile only 21.5 KB; 5 blocks/CU.
// Layer1 via bf16 MFMA (W hi+lo from L2), layers 2/3 + score + half-group
// softmax partial on wave 0. Partial {m,S,V[20]} -> ws.
// ---------------------------------------------------------------------------
#define ASTR 336   // LDS A-row stride bytes (168 shorts; 160 data + pad), 16B-aligned
#define H1STR 53   // h1 row stride in floats (21t mod 32 bijective -> conflict-free)

__global__ __launch_bounds__(256, 5)
void fused_mlp_half(const float* __restrict__ x,
                    const unsigned short* __restrict__ Bpre,
                    const float* __restrict__ b1a,
                    const float* __restrict__ W1b, const float* __restrict__ b1b,
                    const float* __restrict__ W1c, const float* __restrict__ b1c,
                    const float* __restrict__ pW1, const float* __restrict__ pb1,
                    const float* __restrict__ pW2, const float* __restrict__ pb2,
                    float* __restrict__ partials)
{
    __shared__ __align__(16) char smem[64 * ASTR];   // 21504 B (h1 reuses it)

    const int tid  = threadIdx.x;
    const int wv   = tid >> 6;
    const int lane = tid & 63;
    const int fr   = lane & 15;
    const int kq   = lane >> 4;

    const float* slab = x + (size_t)blockIdx.x * (64 * 318);

    // per-thread stage mapping: f = q*256+tid -> row = f/80, c2 = f%80
    int s_row[20], s_c2[20];
    #pragma unroll
    for (int q = 0; q < 20; ++q) {
        int f = q * 256 + tid;
        s_row[q] = f / 80;
        s_c2[q]  = f - s_row[q] * 80;
    }

    floatx4 acc[4];
    #pragma unroll
    for (int nf = 0; nf < 4; ++nf) acc[nf] = (floatx4){0.f, 0.f, 0.f, 0.f};

    const char* abase = smem + (wv * 16 + fr) * ASTR + kq * 16;
    const char* bbase = (const char*)Bpre + kq * 1024 + fr * 16;

    #pragma unroll
    for (int st = 0; st < 2; ++st) {
        if (st == 1) __syncthreads();   // stage-0 A reads done before overwrite
        // ---- load this K-half (coalesced float2 runs of 80 per row)
        float2 g[20];
        #pragma unroll
        for (int q = 0; q < 20; ++q) {
            bool pad = (st == 1) && (s_c2[q] == 79);   // k=318,319 zero pad
            g[q] = pad ? make_float2(0.f, 0.f)
                       : *(const float2*)(slab + (size_t)s_row[q] * 318 + st * 160 + 2 * s_c2[q]);
        }
        // ---- convert + LDS write
        #pragma unroll
        for (int q = 0; q < 20; ++q) {
            uint32_t pk = (uint32_t)f32_to_bf16_rne(g[q].x) |
                          ((uint32_t)f32_to_bf16_rne(g[q].y) << 16);
            *(uint32_t*)(smem + s_row[q] * ASTR + s_c2[q] * 4) = pk;
        }
        __syncthreads();

        // ---- 5 K-steps: A from LDS, B (hi+lo) from L2-resident global
        #pragma unroll
        for (int ksl = 0; ksl < 5; ++ksl) {
            const int ks = st * 5 + ksl;
            bf16x8 a = *(const bf16x8*)(abase + ksl * 64);
            #pragma unroll
            for (int nf = 0; nf < 4; ++nf) {
                bf16x8 bh = *(const bf16x8*)(bbase + ks * 8192 + nf * 256);
                bf16x8 bl = *(const bf16x8*)(bbase + ks * 8192 + 4096 + nf * 256);
                acc[nf] = __builtin_amdgcn_mfma_f32_16x16x32_bf16(a, bh, acc[nf], 0, 0, 0);
                acc[nf] = __builtin_amdgcn_mfma_f32_16x16x32_bf16(a, bl, acc[nf], 0, 0, 0);
            }
        }
    }
    __syncthreads();   // all A reads done before h1 overwrite

    // ---- bias + ReLU -> h1 [64][53] f32 in LDS (reuses A buffer)
    float* h1 = (float*)smem;
    #pragma unroll
    for (int nf = 0; nf < 4; ++nf) {
        int n = nf * 16 + fr;
        if (n < 50) {
            float bia = b1a[n];
            #pragma unroll
            for (int r = 0; r < 4; ++r) {
                int m = wv * 16 + kq * 4 + r;     // D row = (lane>>4)*4 + reg
                h1[m * H1STR + n] = fmaxf(acc[nf][r] + bia, 0.0f);
            }
        }
    }
    __syncthreads();

    if (wv != 0) return;   // waves 1-3 done; no further barriers

    // ---- wave 0: token t = lane; layer 2 streams h1 from LDS (saves VGPRs)
    const float* h1row = h1 + lane * H1STR;

    float h2[20];
    #pragma unroll
    for (int o = 0; o < 20; ++o) h2[o] = b1b[o];
    #pragma unroll
    for (int i = 0; i < 50; ++i) {
        float hv = h1row[i];
        #pragma unroll
        for (int o = 0; o < 20; ++o) h2[o] = fmaf(hv, W1b[o * 50 + i], h2[o]);
    }
    #pragma unroll
    for (int o = 0; o < 20; ++o) h2[o] = fmaxf(h2[o], 0.0f);

    float h3[20];
    #pragma unroll
    for (int o = 0; o < 20; ++o) {
        float a = b1c[o];
        const float* w = W1c + o * 20;
        #pragma unroll
        for (int i = 0; i < 20; ++i) a = fmaf(h2[i], w[i], a);
        h3[o] = fmaxf(a, 0.0f);
    }

    float s = pb2[0];
    #pragma unroll
    for (int j = 0; j < 10; ++j) {
        float a = pb1[j];
        const float* w = pW1 + j * 20;
        #pragma unroll
        for (int i = 0; i < 20; ++i) a = fmaf(h3[i], w[i], a);
        s = fmaf(fmaxf(a, 0.0f), pW2[j], s);
    }

    // softmax partial over the 64 tokens of this half-group (full wave)
    float m = s;
    #pragma unroll
    for (int d = 32; d > 0; d >>= 1) m = fmaxf(m, __shfl_xor(m, d));

    float e = expf(s - m);
    float S = e;
    #pragma unroll
    for (int d = 32; d > 0; d >>= 1) S += __shfl_xor(S, d);

    float V[20];
    #pragma unroll
    for (int o = 0; o < 20; ++o) {
        float v = e * h3[o];
        #pragma unroll
        for (int d = 32; d > 0; d >>= 1) v += __shfl_xor(v, d);
        V[o] = v;
    }

    // lanes 0..21 write {m, S, V[0..19]} as one coalesced 88B burst
    float myv = m;
    if (lane == 1) myv = S;
    #pragma unroll
    for (int o = 0; o < 20; ++o) if (lane == o + 2) myv = V[o];
    if (lane < 22) partials[(size_t)blockIdx.x * 24 + lane] = myv;
}

// ---------------------------------------------------------------------------
// Kernel B: combine half-group partials, pool over G=128, normalize, head.
// ---------------------------------------------------------------------------
__global__ __launch_bounds__(128, 4)
void pool_g_head(const float* __restrict__ partials,
                 const float* __restrict__ qW1, const float* __restrict__ qb1,
                 const float* __restrict__ qW2, const float* __restrict__ qb2,
                 const float* __restrict__ W3a, const float* __restrict__ b3a,
                 const float* __restrict__ W3b, const float* __restrict__ b3b,
                 float* __restrict__ out)
{
    __shared__ float red_m[2];
    __shared__ float red_s[2];
    __shared__ float part[2][20];

    const int tid = threadIdx.x;      // g
    const int b = blockIdx.x;
    const float* P = partials + ((size_t)(b * 128 + tid)) * 48;

    float m0 = P[0], S0 = P[1], m1 = P[24], S1 = P[25];
    float m = fmaxf(m0, m1);
    float w0 = expf(m0 - m), w1 = expf(m1 - m);
    float den = fmaf(S0, w0, S1 * w1);

    float v[20];
    #pragma unroll
    for (int o = 0; o < 20; ++o)
        v[o] = fmaf(P[2 + o], w0, P[26 + o] * w1) / den;

    float s = qb2[0];
    #pragma unroll
    for (int j = 0; j < 10; ++j) {
        float a = qb1[j];
        const float* w = qW1 + j * 20;
        #pragma unroll
        for (int i = 0; i < 20; ++i) a = fmaf(v[i], w[i], a);
        s = fmaf(fmaxf(a, 0.0f), qW2[j], s);
    }

    const int wig = tid >> 6, lane = tid & 63;
    float mm = s;
    #pragma unroll
    for (int d = 32; d > 0; d >>= 1) mm = fmaxf(mm, __shfl_xor(mm, d));
    if (lane == 0) red_m[wig] = mm;
    __syncthreads();
    mm = fmaxf(red_m[0], red_m[1]);

    float e = expf(s - mm);
    float su = e;
    #pragma unroll
    for (int d = 32; d > 0; d >>= 1) su += __shfl_xor(su, d);
    if (lane == 0) red_s[wig] = su;

    #pragma unroll
    for (int o = 0; o < 20; ++o) {
        float val = e * v[o];
        #pragma unroll
        for (int d = 32; d > 0; d >>= 1) val += __shfl_xor(val, d);
        if (lane == 0) part[wig][o] = val;
    }
    __syncthreads();

    if (tid == 0) {
        float dg = red_s[0] + red_s[1];
        float rb[20];
        float n2 = 0.0f;
        #pragma unroll
        for (int o = 0; o < 20; ++o) {
            rb[o] = (part[0][o] + part[1][o]) / dg;
            n2 = fmaf(rb[o], rb[o], n2);
        }
        float nrm = fmaxf(sqrtf(n2), 1e-12f);
        #pragma unroll
        for (int o = 0; o < 20; ++o) rb[o] /= nrm;

        float accv = b3b[0];
        #pragma unroll
        for (int j = 0; j < 10; ++j) {
            float a = b3a[j];
            const float* w = W3a + j * 20;
            #pragma unroll
            for (int i = 0; i < 20; ++i) a = fmaf(rb[i], w[i], a);
            accv = fmaf(fmaxf(a, 0.0f), W3b[j], accv);
        }
        out[b] = accv;
    }
}

extern "C" void kernel_launch(void* const* d_in, const int* in_sizes, int n_in,
                              void* d_out, int out_size, void* d_ws, size_t ws_size,
                              hipStream_t stream) {
    const float* x   = (const float*)d_in[0];
    const float* W1a = (const float*)d_in[1];
    const float* b1a = (const float*)d_in[2];
    const float* W1b = (const float*)d_in[3];
    const float* b1b = (const float*)d_in[4];
    const float* W1c = (const float*)d_in[5];
    const float* b1c = (const float*)d_in[6];
    const float* pW1 = (const float*)d_in[7];
    const float* pb1 = (const float*)d_in[8];
    const float* pW2 = (const float*)d_in[9];
    const float* pb2 = (const float*)d_in[10];
    const float* qW1 = (const float*)d_in[11];
    const float* qb1 = (const float*)d_in[12];
    const float* qW2 = (const float*)d_in[13];
    const float* qb2 = (const float*)d_in[14];
    const float* W3a = (const float*)d_in[15];
    const float* b3a = (const float*)d_in[16];
    const float* W3b = (const float*)d_in[17];
    const float* b3b = (const float*)d_in[18];

    float* partials      = (float*)d_ws;                             // 786,432 B
    unsigned short* Bpre = (unsigned short*)((char*)d_ws + 786432);  // 81,920 B

    prep_w<<<160, 256, 0, stream>>>(W1a, Bpre);
    fused_mlp_half<<<8192, 256, 0, stream>>>(
        x, Bpre, b1a, W1b, b1b, W1c, b1c, pW1, pb1, pW2, pb2, partials);
    pool_g_head<<<32, 128, 0, stream>>>(
        partials, qW1, qb1, qW2, qb2, W3a, b3a, W3b, b3b, (float*)d_out);
}

// Round 5
// 390.106 us; speedup vs baseline: 1.1492x; 1.1492x over previous
//
#include <hip/hip_runtime.h>
#include <math.h>
#include <stdint.h>

typedef __attribute__((ext_vector_type(8))) short bf16x8;
typedef __attribute__((ext_vector_type(4))) float floatx4;

static __device__ __forceinline__ unsigned short f32_to_bf16_rne(float f) {
    union { float f; uint32_t u; } v; v.f = f;
    uint32_t u = v.u;
    return (unsigned short)((u + 0x7fffu + ((u >> 16) & 1u)) >> 16);
}
static __device__ __forceinline__ float bf16_to_f32(unsigned short h) {
    union { uint32_t u; float f; } v; v.u = ((uint32_t)h) << 16;
    return v.f;
}
static __device__ __forceinline__ uint32_t pack2(float2 a) {
    return (uint32_t)f32_to_bf16_rne(a.x) | ((uint32_t)f32_to_bf16_rne(a.y) << 16);
}

// ---------------------------------------------------------------------------
// Prep: W1a (50x318) -> hi/lo bf16, fragment-ordered:
// Bpre[ks][part][kq][n][8 bf16]; byte = ks*8192 + p*4096 + kq*1024 + n*16.
// ---------------------------------------------------------------------------
__global__ void prep_w(const float* __restrict__ W1a, unsigned short* __restrict__ Bpre) {
    int idx = blockIdx.x * 256 + threadIdx.x;
    if (idx >= 40960) return;
    int e  = idx & 7;
    int n  = (idx >> 3) & 63;
    int kq = (idx >> 9) & 3;
    int p  = (idx >> 11) & 1;
    int ks = idx >> 12;
    int k  = ks * 32 + kq * 8 + e;
    float w = (n < 50 && k < 318) ? W1a[n * 318 + k] : 0.0f;
    unsigned short hi = f32_to_bf16_rne(w);
    Bpre[idx] = (p == 0) ? hi : f32_to_bf16_rne(w - bf16_to_f32(hi));
}

// ---------------------------------------------------------------------------
// Kernel A: 64 tokens/block, 8192 blocks, 256 threads.
// 2 K-stages (160 floats each). Per stage: A-half (bf16, [64] rows x 336B
// stride) + B-half (40,960B, layout = global) both in LDS, single-buffered.
// Wave tile 32 rows x 32 n. Stage-1 global loads prefetched into regs across
// stage-0 compute. Tail (layers 2/3 + score + 64-token softmax partial) on
// wave 0. No index arrays, batches <= 80 VGPR -> no spill (cap 256).
// ---------------------------------------------------------------------------
#define A_STR 336
#define B_OFF 21504
#define H1STR 53

__global__ __launch_bounds__(256, 2)
void fused_mlp_half(const float* __restrict__ x,
                    const unsigned short* __restrict__ Bpre,
                    const float* __restrict__ b1a,
                    const float* __restrict__ W1b, const float* __restrict__ b1b,
                    const float* __restrict__ W1c, const float* __restrict__ b1c,
                    const float* __restrict__ pW1, const float* __restrict__ pb1,
                    const float* __restrict__ pW2, const float* __restrict__ pb2,
                    float* __restrict__ partials)
{
    __shared__ __align__(16) char smem[62464];   // 21504 (A) + 40960 (B)

    const int tid  = threadIdx.x;
    const int wv   = tid >> 6;
    const int lane = tid & 63;
    const int fr   = lane & 15;
    const int kq   = lane >> 4;
    const int r0   = (wv & 1) * 32;     // wave row block
    const int c0   = (wv >> 1) * 32;    // wave col block

    const float* slab = x + (size_t)blockIdx.x * (64 * 318);
    const char*  bsrc = (const char*)Bpre;

    floatx4 acc[2][2];
    #pragma unroll
    for (int mi = 0; mi < 2; ++mi)
        #pragma unroll
        for (int nf = 0; nf < 2; ++nf) acc[mi][nf] = (floatx4){0.f, 0.f, 0.f, 0.f};

    float2  ga[20];   // A-half staging: f = j*256+tid over [64][80] float2 grid
    floatx4 gb[10];   // B-half staging: linear 2560 float4

    // ---- stage 0: load + write
    #pragma unroll
    for (int j = 0; j < 20; ++j) {
        int f = j * 256 + tid; int row = f / 80, c2 = f - row * 80;
        ga[j] = *(const float2*)(slab + row * 318 + 2 * c2);
    }
    #pragma unroll
    for (int j = 0; j < 10; ++j)
        gb[j] = *(const floatx4*)(bsrc + (j * 256 + tid) * 16);
    #pragma unroll
    for (int j = 0; j < 20; ++j) {
        int f = j * 256 + tid; int row = f / 80, c2 = f - row * 80;
        *(uint32_t*)(smem + row * A_STR + c2 * 4) = pack2(ga[j]);
    }
    #pragma unroll
    for (int j = 0; j < 10; ++j)
        *(floatx4*)(smem + B_OFF + (j * 256 + tid) * 16) = gb[j];
    __syncthreads();

    // ---- prefetch stage 1 into regs (in flight across stage-0 compute)
    #pragma unroll
    for (int j = 0; j < 20; ++j) {
        int f = j * 256 + tid; int row = f / 80, c2 = f - row * 80;
        ga[j] = (c2 < 79) ? *(const float2*)(slab + row * 318 + 160 + 2 * c2)
                          : make_float2(0.f, 0.f);   // k=318,319 zero pad
    }
    #pragma unroll
    for (int j = 0; j < 10; ++j)
        gb[j] = *(const floatx4*)(bsrc + 40960 + (j * 256 + tid) * 16);
    __builtin_amdgcn_sched_barrier(0);   // pin loads above compute

    const char* ab = smem + (r0 + fr) * A_STR + kq * 16;
    const char* bb = smem + B_OFF + kq * 1024 + (c0 << 4) + fr * 16;

#define COMPUTE() { \
    _Pragma("unroll") for (int ksl = 0; ksl < 5; ++ksl) { \
        bf16x8 a0 = *(const bf16x8*)(ab + ksl * 64); \
        bf16x8 a1 = *(const bf16x8*)(ab + 16 * A_STR + ksl * 64); \
        _Pragma("unroll") for (int nf = 0; nf < 2; ++nf) { \
            bf16x8 bh = *(const bf16x8*)(bb + ksl * 8192 + nf * 256); \
            bf16x8 bl = *(const bf16x8*)(bb + ksl * 8192 + 4096 + nf * 256); \
            acc[0][nf] = __builtin_amdgcn_mfma_f32_16x16x32_bf16(a0, bh, acc[0][nf], 0, 0, 0); \
            acc[0][nf] = __builtin_amdgcn_mfma_f32_16x16x32_bf16(a0, bl, acc[0][nf], 0, 0, 0); \
            acc[1][nf] = __builtin_amdgcn_mfma_f32_16x16x32_bf16(a1, bh, acc[1][nf], 0, 0, 0); \
            acc[1][nf] = __builtin_amdgcn_mfma_f32_16x16x32_bf16(a1, bl, acc[1][nf], 0, 0, 0); \
        } \
    } }

    COMPUTE();            // stage 0
    __syncthreads();      // all stage-0 LDS reads done

    // ---- write stage 1
    #pragma unroll
    for (int j = 0; j < 20; ++j) {
        int f = j * 256 + tid; int row = f / 80, c2 = f - row * 80;
        *(uint32_t*)(smem + row * A_STR + c2 * 4) = pack2(ga[j]);
    }
    #pragma unroll
    for (int j = 0; j < 10; ++j)
        *(floatx4*)(smem + B_OFF + (j * 256 + tid) * 16) = gb[j];
    __syncthreads();

    COMPUTE();            // stage 1
    __syncthreads();      // all stage-1 LDS reads done before h1 overwrite
#undef COMPUTE

    // ---- bias + ReLU -> h1 [64][53] f32 (reuses A region)
    float* h1 = (float*)smem;
    #pragma unroll
    for (int mi = 0; mi < 2; ++mi)
        #pragma unroll
        for (int nf = 0; nf < 2; ++nf) {
            int n = c0 + nf * 16 + fr;
            if (n < 50) {
                float bia = b1a[n];
                #pragma unroll
                for (int r = 0; r < 4; ++r) {
                    int m = r0 + mi * 16 + kq * 4 + r;   // D row = (lane>>4)*4 + reg
                    h1[m * H1STR + n] = fmaxf(acc[mi][nf][r] + bia, 0.0f);
                }
            }
        }
    __syncthreads();

    if (wv != 0) return;   // waves 1-3 done

    // ---- wave 0: token t = lane; layer 2 streams h1 from LDS
    const float* h1row = h1 + lane * H1STR;

    float h2[20];
    #pragma unroll
    for (int o = 0; o < 20; ++o) h2[o] = b1b[o];
    #pragma unroll
    for (int i = 0; i < 50; ++i) {
        float hv = h1row[i];
        #pragma unroll
        for (int o = 0; o < 20; ++o) h2[o] = fmaf(hv, W1b[o * 50 + i], h2[o]);
    }
    #pragma unroll
    for (int o = 0; o < 20; ++o) h2[o] = fmaxf(h2[o], 0.0f);

    float h3[20];
    #pragma unroll
    for (int o = 0; o < 20; ++o) {
        float a = b1c[o];
        const float* w = W1c + o * 20;
        #pragma unroll
        for (int i = 0; i < 20; ++i) a = fmaf(h2[i], w[i], a);
        h3[o] = fmaxf(a, 0.0f);
    }

    float s = pb2[0];
    #pragma unroll
    for (int j = 0; j < 10; ++j) {
        float a = pb1[j];
        const float* w = pW1 + j * 20;
        #pragma unroll
        for (int i = 0; i < 20; ++i) a = fmaf(h3[i], w[i], a);
        s = fmaf(fmaxf(a, 0.0f), pW2[j], s);
    }

    // softmax partial over this 64-token half-group
    float m = s;
    #pragma unroll
    for (int d = 32; d > 0; d >>= 1) m = fmaxf(m, __shfl_xor(m, d));

    float e = expf(s - m);
    float S = e;
    #pragma unroll
    for (int d = 32; d > 0; d >>= 1) S += __shfl_xor(S, d);

    float V[20];
    #pragma unroll
    for (int o = 0; o < 20; ++o) {
        float v = e * h3[o];
        #pragma unroll
        for (int d = 32; d > 0; d >>= 1) v += __shfl_xor(v, d);
        V[o] = v;
    }

    float myv = m;
    if (lane == 1) myv = S;
    #pragma unroll
    for (int o = 0; o < 20; ++o) if (lane == o + 2) myv = V[o];
    if (lane < 22) partials[(size_t)blockIdx.x * 24 + lane] = myv;
}

// ---------------------------------------------------------------------------
// Kernel B: combine half-group partials, pool over G=128, normalize, head.
// ---------------------------------------------------------------------------
__global__ __launch_bounds__(128, 4)
void pool_g_head(const float* __restrict__ partials,
                 const float* __restrict__ qW1, const float* __restrict__ qb1,
                 const float* __restrict__ qW2, const float* __restrict__ qb2,
                 const float* __restrict__ W3a, const float* __restrict__ b3a,
                 const float* __restrict__ W3b, const float* __restrict__ b3b,
                 float* __restrict__ out)
{
    __shared__ float red_m[2];
    __shared__ float red_s[2];
    __shared__ float part[2][20];

    const int tid = threadIdx.x;      // g
    const int b = blockIdx.x;
    const float* P = partials + ((size_t)(b * 128 + tid)) * 48;

    float m0 = P[0], S0 = P[1], m1 = P[24], S1 = P[25];
    float m = fmaxf(m0, m1);
    float w0 = expf(m0 - m), w1 = expf(m1 - m);
    float den = fmaf(S0, w0, S1 * w1);

    float v[20];
    #pragma unroll
    for (int o = 0; o < 20; ++o)
        v[o] = fmaf(P[2 + o], w0, P[26 + o] * w1) / den;

    float s = qb2[0];
    #pragma unroll
    for (int j = 0; j < 10; ++j) {
        float a = qb1[j];
        const float* w = qW1 + j * 20;
        #pragma unroll
        for (int i = 0; i < 20; ++i) a = fmaf(v[i], w[i], a);
        s = fmaf(fmaxf(a, 0.0f), qW2[j], s);
    }

    const int wig = tid >> 6, lane = tid & 63;
    float mm = s;
    #pragma unroll
    for (int d = 32; d > 0; d >>= 1) mm = fmaxf(mm, __shfl_xor(mm, d));
    if (lane == 0) red_m[wig] = mm;
    __syncthreads();
    mm = fmaxf(red_m[0], red_m[1]);

    float e = expf(s - mm);
    float su = e;
    #pragma unroll
    for (int d = 32; d > 0; d >>= 1) su += __shfl_xor(su, d);
    if (lane == 0) red_s[wig] = su;

    #pragma unroll
    for (int o = 0; o < 20; ++o) {
        float val = e * v[o];
        #pragma unroll
        for (int d = 32; d > 0; d >>= 1) val += __shfl_xor(val, d);
        if (lane == 0) part[wig][o] = val;
    }
    __syncthreads();

    if (tid == 0) {
        float dg = red_s[0] + red_s[1];
        float rb[20];
        float n2 = 0.0f;
        #pragma unroll
        for (int o = 0; o < 20; ++o) {
            rb[o] = (part[0][o] + part[1][o]) / dg;
            n2 = fmaf(rb[o], rb[o], n2);
        }
        float nrm = fmaxf(sqrtf(n2), 1e-12f);
        #pragma unroll
        for (int o = 0; o < 20; ++o) rb[o] /= nrm;

        float accv = b3b[0];
        #pragma unroll
        for (int j = 0; j < 10; ++j) {
            float a = b3a[j];
            const float* w = W3a + j * 20;
            #pragma unroll
            for (int i = 0; i < 20; ++i) a = fmaf(rb[i], w[i], a);
            accv = fmaf(fmaxf(a, 0.0f), W3b[j], accv);
        }
        out[b] = accv;
    }
}

extern "C" void kernel_launch(void* const* d_in, const int* in_sizes, int n_in,
                              void* d_out, int out_size, void* d_ws, size_t ws_size,
                              hipStream_t stream) {
    const float* x   = (const float*)d_in[0];
    const float* W1a = (const float*)d_in[1];
    const float* b1a = (const float*)d_in[2];
    const float* W1b = (const float*)d_in[3];
    const float* b1b = (const float*)d_in[4];
    const float* W1c = (const float*)d_in[5];
    const float* b1c = (const float*)d_in[6];
    const float* pW1 = (const float*)d_in[7];
    const float* pb1 = (const float*)d_in[8];
    const float* pW2 = (const float*)d_in[9];
    const float* pb2 = (const float*)d_in[10];
    const float* qW1 = (const float*)d_in[11];
    const float* qb1 = (const float*)d_in[12];
    const float* qW2 = (const float*)d_in[13];
    const float* qb2 = (const float*)d_in[14];
    const float* W3a = (const float*)d_in[15];
    const float* b3a = (const float*)d_in[16];
    const float* W3b = (const float*)d_in[17];
    const float* b3b = (const float*)d_in[18];

    float* partials      = (float*)d_ws;                             // 786,432 B
    unsigned short* Bpre = (unsigned short*)((char*)d_ws + 786432);  // 81,920 B

    prep_w<<<160, 256, 0, stream>>>(W1a, Bpre);
    fused_mlp_half<<<8192, 256, 0, stream>>>(
        x, Bpre, b1a, W1b, b1b, W1c, b1c, pW1, pb1, pW2, pb2, partials);
    pool_g_head<<<32, 128, 0, stream>>>(
        partials, qW1, qb1, qW2, qb2, W3a, b3a, W3b, b3b, (float*)d_out);
}

// Round 6
// 243.621 us; speedup vs baseline: 1.8402x; 1.6013x over previous
//
#include <hip/hip_runtime.h>
#include <math.h>
#include <stdint.h>

typedef __attribute__((ext_vector_type(8))) short bf16x8;
typedef __attribute__((ext_vector_type(4))) float floatx4;

static __device__ __forceinline__ unsigned short f32_to_bf16_rne(float f) {
    union { float f; uint32_t u; } v; v.f = f;
    uint32_t u = v.u;
    return (unsigned short)((u + 0x7fffu + ((u >> 16) & 1u)) >> 16);
}
static __device__ __forceinline__ float bf16_to_f32(unsigned short h) {
    union { uint32_t u; float f; } v; v.u = ((uint32_t)h) << 16;
    return v.f;
}
static __device__ __forceinline__ uint32_t pack2(float2 a) {
    return (uint32_t)f32_to_bf16_rne(a.x) | ((uint32_t)f32_to_bf16_rne(a.y) << 16);
}

// ---------------------------------------------------------------------------
// Prep: W1a (50x318) -> hi/lo bf16, fragment-ordered:
// byte = ks*8192 + p*4096 + kq*1024 + n*16  (n in [0,64), zero-padded)
// ---------------------------------------------------------------------------
__global__ void prep_w(const float* __restrict__ W1a, unsigned short* __restrict__ Bpre) {
    int idx = blockIdx.x * 256 + threadIdx.x;
    if (idx >= 40960) return;
    int e  = idx & 7;
    int n  = (idx >> 3) & 63;
    int kq = (idx >> 9) & 3;
    int p  = (idx >> 11) & 1;
    int ks = idx >> 12;
    int k  = ks * 32 + kq * 8 + e;
    float w = (n < 50 && k < 318) ? W1a[n * 318 + k] : 0.0f;
    unsigned short hi = f32_to_bf16_rne(w);
    Bpre[idx] = (p == 0) ? hi : f32_to_bf16_rne(w - bf16_to_f32(hi));
}

// ---------------------------------------------------------------------------
// Kernel A: 64 tokens/block, 8192 blocks, 256 threads (4 waves).
// Wave w owns output n-slice [16w,16w+16): B hi/lo fragments in REGISTERS
// (80 VGPR), loaded once from L2-resident Bpre. LDS holds only A: two
// 21KB K-planes (rows x 336B). Single compute phase (80 MFMA). Tail
// (layers 2/3) parallelized across all 4 waves by output slice; score +
// softmax partial on wave 0. Partial {m,S,V[20]} -> ws.
// ---------------------------------------------------------------------------
#define A_STR 336      // bytes per row within a K-plane
#define PLANE 21504    // bytes per K-plane (64 rows)
#define H1S   54       // h1 row stride (floats)
#define H2OFF 14336    // h2 buffer byte offset (after h1's 13824)
#define H2S   22
#define H3S   22

__global__ __launch_bounds__(256, 3)
void fused_mlp(const float* __restrict__ x,
               const unsigned short* __restrict__ Bpre,
               const float* __restrict__ b1a,
               const float* __restrict__ W1b, const float* __restrict__ b1b,
               const float* __restrict__ W1c, const float* __restrict__ b1c,
               const float* __restrict__ pW1, const float* __restrict__ pb1,
               const float* __restrict__ pW2, const float* __restrict__ pb2,
               float* __restrict__ partials)
{
    __shared__ __align__(16) char smem[2 * PLANE];   // 43008 B

    const int tid  = threadIdx.x;
    const int wv   = tid >> 6;
    const int lane = tid & 63;
    const int fr   = lane & 15;
    const int kq   = lane >> 4;
    const int row  = tid >> 2;      // staging: 4 threads per token row
    const int q    = tid & 3;

    const float* slab = x + (size_t)blockIdx.x * (64 * 318);
    const float* rowp = slab + row * 318 + 2 * q;   // thread's k-comb base
    char* wrow = smem + row * A_STR + q * 4;

    // ---- A batch 0 (k 0..159 -> plane 0): 20 coalesced float2, then pack
    {
        float2 a0[20];
        #pragma unroll
        for (int j = 0; j < 20; ++j) a0[j] = *(const float2*)(rowp + 8 * j);
        #pragma unroll
        for (int j = 0; j < 20; ++j)
            *(uint32_t*)(wrow + 16 * j) = pack2(a0[j]);
    }
    // ---- A batch 1 (k 160..319 -> plane 1; last slot is zero pad)
    {
        float2 a1[20];
        #pragma unroll
        for (int j = 0; j < 20; ++j) {
            bool pad = (q == 3) && (j == 19);        // k = 318,319
            a1[j] = pad ? make_float2(0.f, 0.f)
                        : *(const float2*)(rowp + 160 + 8 * j);
        }
        // ---- B fragments into registers (L2-resident, behind A in queue)
        // (declared at function scope below; loads issued here via pointer)
        #pragma unroll
        for (int j = 0; j < 20; ++j)
            *(uint32_t*)(wrow + PLANE + 16 * j) = pack2(a1[j]);
    }

    // ---- B hi/lo fragments: wave's n-slice = [wv*16, wv*16+16)
    bf16x8 Bh[10], Bl[10];
    {
        const char* bb = (const char*)Bpre + (kq << 10) + ((wv * 16 + fr) << 4);
        #pragma unroll
        for (int ks = 0; ks < 10; ++ks) {
            Bh[ks] = *(const bf16x8*)(bb + ks * 8192);
            Bl[ks] = *(const bf16x8*)(bb + ks * 8192 + 4096);
        }
    }
    __syncthreads();

    // ---- compute: 10 K-steps x 4 m-frags, hi+lo MFMA (acc in 16 VGPR)
    floatx4 acc[4];
    #pragma unroll
    for (int mi = 0; mi < 4; ++mi) acc[mi] = (floatx4){0.f, 0.f, 0.f, 0.f};

    #pragma unroll
    for (int ks = 0; ks < 10; ++ks) {
        const char* ab = smem + (ks < 5 ? 0 : PLANE) + fr * A_STR
                       + (ks < 5 ? ks : ks - 5) * 64 + kq * 16;
        #pragma unroll
        for (int mi = 0; mi < 4; ++mi) {
            bf16x8 a = *(const bf16x8*)(ab + mi * (16 * A_STR));
            acc[mi] = __builtin_amdgcn_mfma_f32_16x16x32_bf16(a, Bh[ks], acc[mi], 0, 0, 0);
            acc[mi] = __builtin_amdgcn_mfma_f32_16x16x32_bf16(a, Bl[ks], acc[mi], 0, 0, 0);
        }
    }
    __syncthreads();   // all A reads done before h1 overwrite

    // ---- bias + ReLU -> h1 [64][54] f32 (plane-0 region)
    {
        const int n = wv * 16 + fr;
        float* h1 = (float*)smem;
        if (n < 50) {
            float bia = b1a[n];
            #pragma unroll
            for (int mi = 0; mi < 4; ++mi)
                #pragma unroll
                for (int r = 0; r < 4; ++r)
                    h1[(mi * 16 + kq * 4 + r) * H1S + n] = fmaxf(acc[mi][r] + bia, 0.0f);
        }
    }
    __syncthreads();

    // ---- T1: layer2 (50->20), all 4 waves, wave w -> outputs [5w,5w+5)
    const int t = lane;   // token
    {
        float hv[50];
        const float2* h1r = (const float2*)((float*)smem + t * H1S);
        #pragma unroll
        for (int i2 = 0; i2 < 25; ++i2) {
            float2 u = h1r[i2];
            hv[2 * i2] = u.x; hv[2 * i2 + 1] = u.y;
        }
        float* h2b = (float*)(smem + H2OFF);
        #pragma unroll
        for (int oo = 0; oo < 5; ++oo) {
            int o = wv * 5 + oo;
            float a = b1b[o];
            const float* w = W1b + o * 50;
            #pragma unroll
            for (int i = 0; i < 50; ++i) a = fmaf(hv[i], w[i], a);
            h2b[t * H2S + o] = fmaxf(a, 0.0f);
        }
    }
    __syncthreads();

    // ---- T2: layer3 (20->20), wave w -> outputs [5w,5w+5)
    {
        float h2v[20];
        const float2* h2r = (const float2*)((float*)(smem + H2OFF) + t * H2S);
        #pragma unroll
        for (int i2 = 0; i2 < 10; ++i2) {
            float2 u = h2r[i2];
            h2v[2 * i2] = u.x; h2v[2 * i2 + 1] = u.y;
        }
        float* h3b = (float*)(smem + PLANE);
        #pragma unroll
        for (int oo = 0; oo < 5; ++oo) {
            int o = wv * 5 + oo;
            float a = b1c[o];
            const float* w = W1c + o * 20;
            #pragma unroll
            for (int i = 0; i < 20; ++i) a = fmaf(h2v[i], w[i], a);
            h3b[t * H3S + o] = fmaxf(a, 0.0f);
        }
    }
    __syncthreads();

    if (wv != 0) return;   // waves 1-3 done; wave 0 runs barrier-free below

    // ---- T3 (wave 0): score, softmax over 64 tokens, partial {m,S,V}
    float h3v[20];
    {
        const float2* h3r = (const float2*)((float*)(smem + PLANE) + t * H3S);
        #pragma unroll
        for (int i2 = 0; i2 < 10; ++i2) {
            float2 u = h3r[i2];
            h3v[2 * i2] = u.x; h3v[2 * i2 + 1] = u.y;
        }
    }
    float s = pb2[0];
    #pragma unroll
    for (int j = 0; j < 10; ++j) {
        float a = pb1[j];
        const float* w = pW1 + j * 20;
        #pragma unroll
        for (int i = 0; i < 20; ++i) a = fmaf(h3v[i], w[i], a);
        s = fmaf(fmaxf(a, 0.0f), pW2[j], s);
    }

    float m = s;
    #pragma unroll
    for (int d = 32; d > 0; d >>= 1) m = fmaxf(m, __shfl_xor(m, d));

    float e = expf(s - m);
    float S = e;
    #pragma unroll
    for (int d = 32; d > 0; d >>= 1) S += __shfl_xor(S, d);

    float V[20];
    #pragma unroll
    for (int o = 0; o < 20; ++o) {
        float v = e * h3v[o];
        #pragma unroll
        for (int d = 32; d > 0; d >>= 1) v += __shfl_xor(v, d);
        V[o] = v;
    }

    float myv = m;
    if (lane == 1) myv = S;
    #pragma unroll
    for (int o = 0; o < 20; ++o) if (lane == o + 2) myv = V[o];
    if (lane < 22) partials[(size_t)blockIdx.x * 24 + lane] = myv;
}

// ---------------------------------------------------------------------------
// Kernel B: combine half-group partials, pool over G=128, normalize, head.
// ---------------------------------------------------------------------------
__global__ __launch_bounds__(128, 4)
void pool_g_head(const float* __restrict__ partials,
                 const float* __restrict__ qW1, const float* __restrict__ qb1,
                 const float* __restrict__ qW2, const float* __restrict__ qb2,
                 const float* __restrict__ W3a, const float* __restrict__ b3a,
                 const float* __restrict__ W3b, const float* __restrict__ b3b,
                 float* __restrict__ out)
{
    __shared__ float red_m[2];
    __shared__ float red_s[2];
    __shared__ float part[2][20];

    const int tid = threadIdx.x;      // g
    const int b = blockIdx.x;
    const float* P = partials + ((size_t)(b * 128 + tid)) * 48;

    float m0 = P[0], S0 = P[1], m1 = P[24], S1 = P[25];
    float m = fmaxf(m0, m1);
    float w0 = expf(m0 - m), w1 = expf(m1 - m);
    float den = fmaf(S0, w0, S1 * w1);

    float v[20];
    #pragma unroll
    for (int o = 0; o < 20; ++o)
        v[o] = fmaf(P[2 + o], w0, P[26 + o] * w1) / den;

    float s = qb2[0];
    #pragma unroll
    for (int j = 0; j < 10; ++j) {
        float a = qb1[j];
        const float* w = qW1 + j * 20;
        #pragma unroll
        for (int i = 0; i < 20; ++i) a = fmaf(v[i], w[i], a);
        s = fmaf(fmaxf(a, 0.0f), qW2[j], s);
    }

    const int wig = tid >> 6, lane = tid & 63;
    float mm = s;
    #pragma unroll
    for (int d = 32; d > 0; d >>= 1) mm = fmaxf(mm, __shfl_xor(mm, d));
    if (lane == 0) red_m[wig] = mm;
    __syncthreads();
    mm = fmaxf(red_m[0], red_m[1]);

    float e = expf(s - mm);
    float su = e;
    #pragma unroll
    for (int d = 32; d > 0; d >>= 1) su += __shfl_xor(su, d);
    if (lane == 0) red_s[wig] = su;

    #pragma unroll
    for (int o = 0; o < 20; ++o) {
        float val = e * v[o];
        #pragma unroll
        for (int d = 32; d > 0; d >>= 1) val += __shfl_xor(val, d);
        if (lane == 0) part[wig][o] = val;
    }
    __syncthreads();

    if (tid == 0) {
        float dg = red_s[0] + red_s[1];
        float rb[20];
        float n2 = 0.0f;
        #pragma unroll
        for (int o = 0; o < 20; ++o) {
            rb[o] = (part[0][o] + part[1][o]) / dg;
            n2 = fmaf(rb[o], rb[o], n2);
        }
        float nrm = fmaxf(sqrtf(n2), 1e-12f);
        #pragma unroll
        for (int o = 0; o < 20; ++o) rb[o] /= nrm;

        float accv = b3b[0];
        #pragma unroll
        for (int j = 0; j < 10; ++j) {
            float a = b3a[j];
            const float* w = W3a + j * 20;
            #pragma unroll
            for (int i = 0; i < 20; ++i) a = fmaf(rb[i], w[i], a);
            accv = fmaf(fmaxf(a, 0.0f), W3b[j], accv);
        }
        out[b] = accv;
    }
}

extern "C" void kernel_launch(void* const* d_in, const int* in_sizes, int n_in,
                              void* d_out, int out_size, void* d_ws, size_t ws_size,
                              hipStream_t stream) {
    const float* x   = (const float*)d_in[0];
    const float* W1a = (const float*)d_in[1];
    const float* b1a = (const float*)d_in[2];
    const float* W1b = (const float*)d_in[3];
    const float* b1b = (const float*)d_in[4];
    const float* W1c = (const float*)d_in[5];
    const float* b1c = (const float*)d_in[6];
    const float* pW1 = (const float*)d_in[7];
    const float* pb1 = (const float*)d_in[8];
    const float* pW2 = (const float*)d_in[9];
    const float* pb2 = (const float*)d_in[10];
    const float* qW1 = (const float*)d_in[11];
    const float* qb1 = (const float*)d_in[12];
    const float* qW2 = (const float*)d_in[13];
    const float* qb2 = (const float*)d_in[14];
    const float* W3a = (const float*)d_in[15];
    const float* b3a = (const float*)d_in[16];
    const float* W3b = (const float*)d_in[17];
    const float* b3b = (const float*)d_in[18];

    float* partials      = (float*)d_ws;                             // 786,432 B
    unsigned short* Bpre = (unsigned short*)((char*)d_ws + 786432);  // 81,920 B

    prep_w<<<160, 256, 0, stream>>>(W1a, Bpre);
    fused_mlp<<<8192, 256, 0, stream>>>(
        x, Bpre, b1a, W1b, b1b, W1c, b1c, pW1, pb1, pW2, pb2, partials);
    pool_g_head<<<32, 128, 0, stream>>>(
        partials, qW1, qb1, qW2, qb2, W3a, b3a, W3b, b3b, (float*)d_out);
}